// Round 1
// baseline (786.466 us; speedup 1.0000x reference)
//
#include <hip/hip_runtime.h>
#include <hip/hip_bf16.h>
#include <stdint.h>

#define N_ROWS 200000
#define C_DIM  128
#define TAPS   27
#define EPS    1e-5f

typedef __attribute__((ext_vector_type(8)))  short  short8;
typedef __attribute__((ext_vector_type(16))) float  floatx16;

__device__ __forceinline__ unsigned int f2bf(float f) {
  union { float f; unsigned int u; } v; v.f = f;
  unsigned int r = v.u + 0x7FFFu + ((v.u >> 16) & 1u);   // RNE, inputs are finite
  return r >> 16;
}

// ---------------- feats fp32 -> bf16 ----------------
__global__ __launch_bounds__(256) void k_cast(const float* __restrict__ in,
                                              unsigned short* __restrict__ out, int n8) {
  int i = blockIdx.x * 256 + threadIdx.x;
  if (i >= n8) return;
  const float4* p = (const float4*)in + (size_t)i * 2;
  float4 a = p[0], b = p[1];
  uint4 v;
  v.x = f2bf(a.x) | (f2bf(a.y) << 16);
  v.y = f2bf(a.z) | (f2bf(a.w) << 16);
  v.z = f2bf(b.x) | (f2bf(b.y) << 16);
  v.w = f2bf(b.z) | (f2bf(b.w) << 16);
  *(uint4*)(out + (size_t)i * 8) = v;
}

// ---- fold Linear into conv weights; emit MFMA B-fragment layout ----
// wfrag[k][nt(4)][s(8)][lane(64)][j(8)]  (bf16)
//   B-operand of mfma_f32_32x32x16_bf16: lane holds B[kk=(l>>5)*8+j][n=l&31]
//   kk_global = s*16 + (l>>5)*8 + j ; co = nt*32 + (l&31)
//   W'[k][ci][co] = sum_t conv_w[k][ci][t] * lin_w[co][t]
__global__ __launch_bounds__(256) void k_fold(const float* __restrict__ conv_w,
                                              const float* __restrict__ lin_w,
                                              const float* __restrict__ conv_b,
                                              const float* __restrict__ lin_b,
                                              unsigned short* __restrict__ wfrag,
                                              float* __restrict__ biasf) {
  int id = blockIdx.x * 256 + threadIdx.x;
  const int NW = TAPS * 4 * 8 * 64;
  if (id < NW) {
    int l  = id & 63;
    int s  = (id >> 6) & 7;
    int nt = (id >> 9) & 3;
    int k  = id >> 11;
    int ci0 = s * 16 + (l >> 5) * 8;
    int co  = nt * 32 + (l & 31);
    const float* cw = conv_w + ((size_t)(k * 128 + ci0)) * 128;
    const float* lw = lin_w + (size_t)co * 128;
    float acc[8] = {0, 0, 0, 0, 0, 0, 0, 0};
    for (int t = 0; t < 128; ++t) {
      float lv = lw[t];
#pragma unroll
      for (int j = 0; j < 8; ++j) acc[j] += cw[j * 128 + t] * lv;
    }
    uint4 v;
    v.x = f2bf(acc[0]) | (f2bf(acc[1]) << 16);
    v.y = f2bf(acc[2]) | (f2bf(acc[3]) << 16);
    v.z = f2bf(acc[4]) | (f2bf(acc[5]) << 16);
    v.w = f2bf(acc[6]) | (f2bf(acc[7]) << 16);
    *(uint4*)(wfrag + (size_t)id * 8) = v;
  } else if (id < NW + 128) {
    int co = id - NW;
    const float* lw = lin_w + (size_t)co * 128;
    float s = lin_b[co];
    for (int t = 0; t < 128; ++t) s += conv_b[t] * lw[t];
    biasf[co] = s;
  }
}

// ---------------- fused gather-GEMM + LayerNorm ----------------
// block: 256 thr = 4 waves, tile 128 rows x 128 cols
// wave (w>>1, w&1): rows [wrow,wrow+64), cols [wcol,wcol+64) as 2x2 mfma 32x32 tiles
__global__ __launch_bounds__(256, 2) void k_main(const unsigned short* __restrict__ featsB,
                                                 const int* __restrict__ nidx,
                                                 const unsigned short* __restrict__ wfrag,
                                                 const float* __restrict__ biasf,
                                                 const float* __restrict__ lnw,
                                                 const float* __restrict__ lnb,
                                                 float* __restrict__ out) {
  __shared__ unsigned short ldsA[128 * 128];  // [row][chunk^(row&7)][8] bf16, 32 KB
  __shared__ float sSum[256];
  __shared__ float sSq[256];
  __shared__ float sMu[128];
  __shared__ float sRs[128];

  const int tid  = threadIdx.x;
  const int lane = tid & 63;
  const int w    = tid >> 6;
  const int row0 = blockIdx.x * 128;
  const int wrow = (w >> 1) * 64;
  const int ntb  = (w & 1) * 2;
  const int wcol = ntb * 32;
  const int l31  = lane & 31;
  const int lh   = lane >> 5;

  floatx16 acc00 = {0.f}, acc01 = {0.f}, acc10 = {0.f}, acc11 = {0.f};

  const int sc  = tid & 15;   // 16B chunk within row
  const int smb = tid >> 4;   // row within 16-row batch

  for (int k = 0; k < TAPS; ++k) {
    __syncthreads();
    // ---- stage gathered A tile (128 rows x 256B) ----
#pragma unroll
    for (int it = 0; it < 8; ++it) {
      int m  = it * 16 + smb;
      int gr = row0 + m;
      int src = (gr < N_ROWS) ? nidx[(size_t)gr * TAPS + k] : 0;
      uint4 v = *(const uint4*)(featsB + (size_t)src * 128 + sc * 8);
      *(uint4*)(ldsA + (m * 16 + (sc ^ (m & 7))) * 8) = v;
    }
    __syncthreads();
    // ---- compute: 8 k-steps x 4 mfma ----
    const unsigned short* bbase = wfrag + (size_t)((k * 4 + ntb) * 8) * 64 * 8;
#pragma unroll
    for (int s = 0; s < 8; ++s) {
      int kg = s * 2 + lh;
      int m0 = wrow + l31;
      int m1 = m0 + 32;
      short8 a0 = *(const short8*)(ldsA + (m0 * 16 + (kg ^ (m0 & 7))) * 8);
      short8 a1 = *(const short8*)(ldsA + (m1 * 16 + (kg ^ (m1 & 7))) * 8);
      short8 b0 = *(const short8*)(bbase + ((s)*64 + lane) * 8);
      short8 b1 = *(const short8*)(bbase + ((8 + s) * 64 + lane) * 8);
      acc00 = __builtin_amdgcn_mfma_f32_32x32x16_bf16(a0, b0, acc00, 0, 0, 0);
      acc01 = __builtin_amdgcn_mfma_f32_32x32x16_bf16(a0, b1, acc01, 0, 0, 0);
      acc10 = __builtin_amdgcn_mfma_f32_32x32x16_bf16(a1, b0, acc10, 0, 0, 0);
      acc11 = __builtin_amdgcn_mfma_f32_32x32x16_bf16(a1, b1, acc11, 0, 0, 0);
    }
  }

  // ---- epilogue: bias, LayerNorm, store ----
  float b0c = biasf[wcol + l31];
  float b1c = biasf[wcol + 32 + l31];
#pragma unroll
  for (int r = 0; r < 16; ++r) {
    acc00[r] += b0c; acc01[r] += b1c;
    acc10[r] += b0c; acc11[r] += b1c;
  }

  // per-row partial sums: C/D layout col=l&31, row=(r&3)+8*(r>>2)+4*lh
#pragma unroll
  for (int rt = 0; rt < 2; ++rt) {
#pragma unroll
    for (int r = 0; r < 16; ++r) {
      float x0 = rt ? acc10[r] : acc00[r];
      float x1 = rt ? acc11[r] : acc01[r];
      float s = x0 + x1;
      float q = x0 * x0 + x1 * x1;
#pragma unroll
      for (int off = 16; off >= 1; off >>= 1) {
        s += __shfl_xor(s, off, 64);
        q += __shfl_xor(q, off, 64);
      }
      if (l31 == 0) {
        int rl = wrow + rt * 32 + (r & 3) + 8 * (r >> 2) + 4 * lh;
        sSum[rl * 2 + (w & 1)] = s;
        sSq [rl * 2 + (w & 1)] = q;
      }
    }
  }
  __syncthreads();
  if (tid < 128) {
    float S = sSum[tid * 2] + sSum[tid * 2 + 1];
    float Q = sSq [tid * 2] + sSq [tid * 2 + 1];
    float mu  = S * (1.0f / 128.0f);
    float var = Q * (1.0f / 128.0f) - mu * mu;
    sMu[tid] = mu;
    sRs[tid] = rsqrtf(var + EPS);
  }
  __syncthreads();

  float g0 = lnw[wcol + l31],      g1 = lnw[wcol + 32 + l31];
  float c0 = lnb[wcol + l31],      c1 = lnb[wcol + 32 + l31];
#pragma unroll
  for (int rt = 0; rt < 2; ++rt) {
#pragma unroll
    for (int r = 0; r < 16; ++r) {
      int rl = wrow + rt * 32 + (r & 3) + 8 * (r >> 2) + 4 * lh;
      int gr = row0 + rl;
      if (gr < N_ROWS) {
        float mu = sMu[rl], rs = sRs[rl];
        float x0 = rt ? acc10[r] : acc00[r];
        float x1 = rt ? acc11[r] : acc01[r];
        out[(size_t)gr * 128 + wcol + l31]      = (x0 - mu) * rs * g0 + c0;
        out[(size_t)gr * 128 + wcol + 32 + l31] = (x1 - mu) * rs * g1 + c1;
      }
    }
  }
}

extern "C" void kernel_launch(void* const* d_in, const int* in_sizes, int n_in,
                              void* d_out, int out_size, void* d_ws, size_t ws_size,
                              hipStream_t stream) {
  const float* feats  = (const float*)d_in[0];
  const int*   nidx   = (const int*)d_in[1];
  const float* conv_w = (const float*)d_in[2];
  const float* conv_b = (const float*)d_in[3];
  const float* lin_w  = (const float*)d_in[4];
  const float* lin_b  = (const float*)d_in[5];
  const float* ln_w   = (const float*)d_in[6];
  const float* ln_b   = (const float*)d_in[7];
  float* out = (float*)d_out;

  // workspace layout
  unsigned short* featsB = (unsigned short*)d_ws;                          // 51,200,000 B
  unsigned short* wfrag  = (unsigned short*)((char*)d_ws + 51200000);      //    884,736 B
  float*          biasf  = (float*)((char*)d_ws + 51200000 + 884736);      //        512 B

  int n8 = N_ROWS * C_DIM / 8;  // 3,200,000
  k_cast<<<(n8 + 255) / 256, 256, 0, stream>>>(feats, featsB, n8);
  k_fold<<<(TAPS * 2048 + 128 + 255) / 256, 256, 0, stream>>>(conv_w, lin_w, conv_b, lin_b,
                                                              wfrag, biasf);
  k_main<<<(N_ROWS + 127) / 128, 256, 0, stream>>>(featsB, nidx, wfrag, biasf, ln_w, ln_b, out);
}

// Round 2
// 504.093 us; speedup vs baseline: 1.5602x; 1.5602x over previous
//
#include <hip/hip_runtime.h>
#include <hip/hip_bf16.h>
#include <stdint.h>

#define N_ROWS 200000
#define C_DIM  128
#define TAPS   27
#define EPS    1e-5f

typedef __attribute__((ext_vector_type(8)))  short  short8;
typedef __attribute__((ext_vector_type(16))) float  floatx16;

__device__ __forceinline__ unsigned int f2bf(float f) {
  union { float f; unsigned int u; } v; v.f = f;
  unsigned int r = v.u + 0x7FFFu + ((v.u >> 16) & 1u);   // RNE, inputs finite
  return r >> 16;
}

__device__ __forceinline__ void glds16(const unsigned short* g, unsigned short* l) {
  __builtin_amdgcn_global_load_lds(
      (const __attribute__((address_space(1))) unsigned int*)g,
      (__attribute__((address_space(3))) unsigned int*)l, 16, 0, 0);
}

// ---------------- feats fp32 -> bf16 ----------------
__global__ __launch_bounds__(256) void k_cast(const float* __restrict__ in,
                                              unsigned short* __restrict__ out, int n8) {
  int i = blockIdx.x * 256 + threadIdx.x;
  if (i >= n8) return;
  const float4* p = (const float4*)in + (size_t)i * 2;
  float4 a = p[0], b = p[1];
  uint4 v;
  v.x = f2bf(a.x) | (f2bf(a.y) << 16);
  v.y = f2bf(a.z) | (f2bf(a.w) << 16);
  v.z = f2bf(b.x) | (f2bf(b.y) << 16);
  v.w = f2bf(b.z) | (f2bf(b.w) << 16);
  *(uint4*)(out + (size_t)i * 8) = v;
}

// ---- fold Linear into conv weights; emit MFMA B-fragment layout ----
// wfrag[k][nt(4)][s(8)][lane(64)][j(8)] (bf16):
//   B frag of mfma_f32_32x32x16_bf16: lane holds B[kk=(l>>5)*8+j][n=l&31]
//   kk_global = s*16 + (l>>5)*8 + j ; co = nt*32 + (l&31)
// lin_w staged in LDS transposed + XOR-swizzled: lwT[t][co ^ (t&31)]
__global__ __launch_bounds__(256) void k_fold(const float* __restrict__ conv_w,
                                              const float* __restrict__ lin_w,
                                              const float* __restrict__ conv_b,
                                              const float* __restrict__ lin_b,
                                              unsigned short* __restrict__ wfrag,
                                              float* __restrict__ biasf) {
  __shared__ float lwT[128 * 128];  // 64 KB
  for (int e = threadIdx.x; e < 16384; e += 256) {
    int co = e >> 7, t = e & 127;
    lwT[t * 128 + (co ^ (t & 31))] = lin_w[e];
  }
  __syncthreads();

  int id = blockIdx.x * 256 + threadIdx.x;
  const int NW = TAPS * 4 * 8 * 64;  // 55296
  if (id < NW) {
    int l  = id & 63;
    int s  = (id >> 6) & 7;
    int nt = (id >> 9) & 3;
    int k  = id >> 11;
    int ci0 = s * 16 + (l >> 5) * 8;
    int co  = nt * 32 + (l & 31);
    const float* cw = conv_w + ((size_t)(k * 128 + ci0)) * 128;
    float acc[8] = {0, 0, 0, 0, 0, 0, 0, 0};
    for (int t = 0; t < 128; ++t) {
      float lv = lwT[t * 128 + (co ^ (t & 31))];
#pragma unroll
      for (int j = 0; j < 8; ++j) acc[j] += cw[j * 128 + t] * lv;
    }
    uint4 v;
    v.x = f2bf(acc[0]) | (f2bf(acc[1]) << 16);
    v.y = f2bf(acc[2]) | (f2bf(acc[3]) << 16);
    v.z = f2bf(acc[4]) | (f2bf(acc[5]) << 16);
    v.w = f2bf(acc[6]) | (f2bf(acc[7]) << 16);
    *(uint4*)(wfrag + (size_t)id * 8) = v;
  } else if (id < NW + 128) {
    int co = id - NW;
    float s = lin_b[co];
    for (int t = 0; t < 128; ++t) s += conv_b[t] * lwT[t * 128 + (co ^ (t & 31))];
    biasf[co] = s;
  }
}

// ---------------- fused gather-GEMM + LayerNorm ----------------
// 512 thr = 8 waves; wave w owns rows [blk*256 + w*32, +32), ALL 128 cols.
// A: global->register gather (read-once). B: LDS double-buffer via
// global_load_lds, 1-tap lookahead, raw s_barrier + vmcnt(4) (no full drain).
// LayerNorm fully in-wave. No __syncthreads anywhere.
__global__ __launch_bounds__(512, 4) void k_main(const unsigned short* __restrict__ featsB,
                                                 const int* __restrict__ nidx,
                                                 const unsigned short* __restrict__ wfrag,
                                                 const float* __restrict__ biasf,
                                                 const float* __restrict__ lnw,
                                                 const float* __restrict__ lnb,
                                                 float* __restrict__ out) {
  __shared__ unsigned short ldsB[2][16384];  // 2 x 32 KB

  const int tid = threadIdx.x;
  const int l   = tid & 63;
  const int w   = tid >> 6;
  const int l31 = l & 31;
  const int lh  = l >> 5;
  const int row0w = blockIdx.x * 256 + w * 32;
  const int gr  = row0w + l31;
  const int grc = (gr < N_ROWS) ? gr : 0;
  const int* np = nidx + (size_t)grc * TAPS;

  floatx16 acc0 = {0.f}, acc1 = {0.f}, acc2 = {0.f}, acc3 = {0.f};

  // prologue: stage B(0) into buf0
  {
    const unsigned short* src = wfrag + (size_t)tid * 8;
    unsigned short* dst = &ldsB[0][w * 512];
#pragma unroll
    for (int r = 0; r < 4; ++r) glds16(src + r * 4096, dst + r * 4096);
  }
  int nid = np[0];

  for (int k = 0; k < TAPS; ++k) {
    const int cur = k & 1;
    if (k + 1 < TAPS) {
      // prefetch B(k+1) into the other buffer (all waves done reading it:
      // end-of-iter barrier of k-1)
      const unsigned short* src = wfrag + (size_t)(k + 1) * 16384 + (size_t)tid * 8;
      unsigned short* dst = &ldsB[cur ^ 1][w * 512];
#pragma unroll
      for (int r = 0; r < 4; ++r) glds16(src + r * 4096, dst + r * 4096);
      __builtin_amdgcn_s_waitcnt(0xF74);  // vmcnt(4): B(k) landed, B(k+1) in flight
    } else {
      __builtin_amdgcn_s_waitcnt(0xF70);  // vmcnt(0)
    }
    __builtin_amdgcn_s_barrier();         // raw: no compiler vmcnt(0) drain

    // A fragments for tap k (per-lane gather, 32 random rows / wave)
    const short8* ap = (const short8*)(featsB + (size_t)(unsigned)nid * 128 + lh * 8);
    short8 a0 = ap[0],  a1 = ap[2],  a2 = ap[4],  a3 = ap[6];
    short8 a4 = ap[8],  a5 = ap[10], a6 = ap[12], a7 = ap[14];
    int nid_next = (k + 1 < TAPS) ? np[k + 1] : 0;

    const unsigned short* bb = &ldsB[cur][l * 8];
#pragma unroll
    for (int s = 0; s < 8; ++s) {
      short8 av = (s == 0) ? a0 : (s == 1) ? a1 : (s == 2) ? a2 : (s == 3) ? a3
                : (s == 4) ? a4 : (s == 5) ? a5 : (s == 6) ? a6 : a7;
      short8 b0 = *(const short8*)(bb + (0 * 8 + s) * 512);
      short8 b1 = *(const short8*)(bb + (1 * 8 + s) * 512);
      short8 b2 = *(const short8*)(bb + (2 * 8 + s) * 512);
      short8 b3 = *(const short8*)(bb + (3 * 8 + s) * 512);
      acc0 = __builtin_amdgcn_mfma_f32_32x32x16_bf16(av, b0, acc0, 0, 0, 0);
      acc1 = __builtin_amdgcn_mfma_f32_32x32x16_bf16(av, b1, acc1, 0, 0, 0);
      acc2 = __builtin_amdgcn_mfma_f32_32x32x16_bf16(av, b2, acc2, 0, 0, 0);
      acc3 = __builtin_amdgcn_mfma_f32_32x32x16_bf16(av, b3, acc3, 0, 0, 0);
    }
    __builtin_amdgcn_s_barrier();  // all reads of buf[cur] done before overwrite
    nid = nid_next;
  }

  // ---- epilogue: bias + in-wave LayerNorm + store ----
  float b0 = biasf[l31], b1 = biasf[32 + l31], b2 = biasf[64 + l31], b3 = biasf[96 + l31];
  float g0 = lnw[l31],   g1 = lnw[32 + l31],   g2 = lnw[64 + l31],   g3 = lnw[96 + l31];
  float c0 = lnb[l31],   c1 = lnb[32 + l31],   c2 = lnb[64 + l31],   c3 = lnb[96 + l31];

#pragma unroll
  for (int r = 0; r < 16; ++r) {
    float x0 = acc0[r] + b0, x1 = acc1[r] + b1, x2 = acc2[r] + b2, x3 = acc3[r] + b3;
    float s = x0 + x1 + x2 + x3;
    float q = x0 * x0 + x1 * x1 + x2 * x2 + x3 * x3;
#pragma unroll
    for (int off = 16; off >= 1; off >>= 1) {
      s += __shfl_xor(s, off, 64);
      q += __shfl_xor(q, off, 64);
    }
    float mu  = s * (1.0f / 128.0f);
    float var = q * (1.0f / 128.0f) - mu * mu;
    float rs  = rsqrtf(var + EPS);
    int row   = (r & 3) + 8 * (r >> 2) + 4 * lh;  // 32x32 C/D row map
    int grow  = row0w + row;
    if (grow < N_ROWS) {
      float* o = out + (size_t)grow * 128;
      o[l31]      = (x0 - mu) * rs * g0 + c0;
      o[32 + l31] = (x1 - mu) * rs * g1 + c1;
      o[64 + l31] = (x2 - mu) * rs * g2 + c2;
      o[96 + l31] = (x3 - mu) * rs * g3 + c3;
    }
  }
}

extern "C" void kernel_launch(void* const* d_in, const int* in_sizes, int n_in,
                              void* d_out, int out_size, void* d_ws, size_t ws_size,
                              hipStream_t stream) {
  const float* feats  = (const float*)d_in[0];
  const int*   nidx   = (const int*)d_in[1];
  const float* conv_w = (const float*)d_in[2];
  const float* conv_b = (const float*)d_in[3];
  const float* lin_w  = (const float*)d_in[4];
  const float* lin_b  = (const float*)d_in[5];
  const float* ln_w   = (const float*)d_in[6];
  const float* ln_b   = (const float*)d_in[7];
  float* out = (float*)d_out;

  unsigned short* featsB = (unsigned short*)d_ws;                       // 51,200,000 B
  unsigned short* wfrag  = (unsigned short*)((char*)d_ws + 51200000);   //    884,736 B
  float*          biasf  = (float*)((char*)d_ws + 51200000 + 884736);   //        512 B

  int n8 = N_ROWS * C_DIM / 8;  // 3,200,000
  k_cast<<<(n8 + 255) / 256, 256, 0, stream>>>(feats, featsB, n8);
  k_fold<<<(TAPS * 2048 + 128 + 255) / 256, 256, 0, stream>>>(conv_w, lin_w, conv_b, lin_b,
                                                              wfrag, biasf);
  k_main<<<(N_ROWS + 255) / 256, 512, 0, stream>>>(featsB, nidx, wfrag, biasf, ln_w, ln_b, out);
}